// Round 2
// baseline (1066.593 us; speedup 1.0000x reference)
//
#include <hip/hip_runtime.h>
#include <hip/hip_cooperative_groups.h>

namespace cg = cooperative_groups;

#define EPS 1e-5f
#define D4 32  // 128 dims = 32 float4s per row

typedef float __attribute__((ext_vector_type(4))) f32x4;

// Fused single-pass cooperative kernel.
// grid = (64, B), block = 256. Thread t: c4 = t&31 (float4 col), rg = t>>5.
// Each block owns a contiguous chunk of its segment's rows:
//   Phase 1: stream chunk forward, accumulate sum/sumsq, LDS-reduce, atomicAdd.
//   grid.sync()
//   Phase 2: re-read the SAME chunk in REVERSE (tail = most recently touched
//   = L3-resident), normalize, NT-store output.
__global__ __launch_bounds__(256, 4) void pin_fused_kernel(
    const float* __restrict__ x, const int* __restrict__ seqlen,
    float* __restrict__ gsum, float* __restrict__ gsq,
    const float* __restrict__ weight, const float* __restrict__ bias,
    float* __restrict__ out)
{
    const int b   = blockIdx.y;
    const int bx  = blockIdx.x;
    const int nbx = gridDim.x;
    const int start = seqlen[b];
    const int rows  = seqlen[b + 1] - start;
    const int c4 = threadIdx.x & 31;
    const int rg = threadIdx.x >> 5;

    // contiguous chunk [c0, c1) of this segment
    const int c0 = (int)(((long long)rows * bx) / nbx);
    const int c1 = (int)(((long long)rows * (bx + 1)) / nbx);

    const f32x4* xp = (const f32x4*)x + (size_t)start * D4;

    // ---- Phase 1: partial sums over chunk (forward, cached loads) ----
    f32x4 sum = 0.f, sq = 0.f;
    {
        int r = c0 + rg;
        for (; r + 8 < c1; r += 16) {
            f32x4 v0 = xp[(size_t)r * D4 + c4];
            f32x4 v1 = xp[(size_t)(r + 8) * D4 + c4];
            sum += v0; sq += v0 * v0;
            sum += v1; sq += v1 * v1;
        }
        if (r < c1) {
            f32x4 v = xp[(size_t)r * D4 + c4];
            sum += v; sq += v * v;
        }
    }

    __shared__ f32x4 ssum[256];
    __shared__ f32x4 ssq[256];
    ssum[threadIdx.x] = sum;
    ssq[threadIdx.x]  = sq;
    __syncthreads();

    if (threadIdx.x < 32) {
        f32x4 ts = ssum[threadIdx.x];
        f32x4 tq = ssq[threadIdx.x];
        #pragma unroll
        for (int g = 1; g < 8; ++g) {
            ts += ssum[g * 32 + threadIdx.x];
            tq += ssq[g * 32 + threadIdx.x];
        }
        float* gs = gsum + b * 128 + threadIdx.x * 4;
        float* gq = gsq  + b * 128 + threadIdx.x * 4;
        atomicAdd(gs + 0, ts.x); atomicAdd(gs + 1, ts.y);
        atomicAdd(gs + 2, ts.z); atomicAdd(gs + 3, ts.w);
        atomicAdd(gq + 0, tq.x); atomicAdd(gq + 1, tq.y);
        atomicAdd(gq + 2, tq.z); atomicAdd(gq + 3, tq.w);
    }
    __threadfence();
    cg::this_grid().sync();

    // ---- Phase 2: normalize own chunk in reverse (tail-first for L3 hits) ----
    const float inv_n = 1.0f / fmaxf((float)rows, 1.0f);
    const int d = c4 * 4;
    f32x4 s  = *(const f32x4*)(gsum + b * 128 + d);
    f32x4 q  = *(const f32x4*)(gsq  + b * 128 + d);
    f32x4 w  = *(const f32x4*)(weight + d);
    f32x4 bi = *(const f32x4*)(bias + d);

    f32x4 m   = s * inv_n;
    f32x4 var = q * inv_n - m * m;
    f32x4 is;
    is.x = rsqrtf(var.x + EPS);
    is.y = rsqrtf(var.y + EPS);
    is.z = rsqrtf(var.z + EPS);
    is.w = rsqrtf(var.w + EPS);
    f32x4 scale = w * is;
    f32x4 shift = bi - m * scale;

    f32x4* op = (f32x4*)out + (size_t)start * D4;
    const int len = c1 - c0;
    const int ng  = (len + 7) >> 3;  // 8-row groups in chunk

    int g = ng - 1;
    if (g >= 0) {  // peel possibly-partial top group
        int r = c0 + g * 8 + rg;
        if (r < c1) {
            size_t idx = (size_t)r * D4 + c4;
            f32x4 v = __builtin_nontemporal_load(xp + idx);
            __builtin_nontemporal_store(v * scale + shift, op + idx);
        }
        --g;
    }
    for (; g >= 1; g -= 2) {  // full groups, 2-way unrolled
        size_t i0 = (size_t)(c0 + g * 8 + rg) * D4 + c4;
        size_t i1 = i0 - (size_t)8 * D4;
        f32x4 v0 = __builtin_nontemporal_load(xp + i0);
        f32x4 v1 = __builtin_nontemporal_load(xp + i1);
        __builtin_nontemporal_store(v0 * scale + shift, op + i0);
        __builtin_nontemporal_store(v1 * scale + shift, op + i1);
    }
    if (g == 0) {
        size_t idx = (size_t)(c0 + rg) * D4 + c4;
        f32x4 v = __builtin_nontemporal_load(xp + idx);
        __builtin_nontemporal_store(v * scale + shift, op + idx);
    }
}

extern "C" void kernel_launch(void* const* d_in, const int* in_sizes, int n_in,
                              void* d_out, int out_size, void* d_ws, size_t ws_size,
                              hipStream_t stream) {
    const float* x      = (const float*)d_in[0];
    const int*   seqlen = (const int*)d_in[1];
    const float* weight = (const float*)d_in[2];
    const float* bias   = (const float*)d_in[3];
    float* out = (float*)d_out;

    const int B = in_sizes[1] - 1;            // 16
    float* gsum = (float*)d_ws;               // [B][128]
    float* gsq  = gsum + (size_t)B * 128;     // [B][128]

    // Workspace is poisoned before every launch — zero the accumulators.
    hipMemsetAsync(d_ws, 0, (size_t)B * 128 * 2 * sizeof(float), stream);

    // 64x16 = 1024 blocks = 4 blocks/CU on 256 CUs: guaranteed co-resident
    // for the cooperative launch (VGPR/LDS fit 4/CU with huge margin).
    dim3 block(256);
    dim3 grid(64, B);
    void* args[] = {(void*)&x, (void*)&seqlen, (void*)&gsum, (void*)&gsq,
                    (void*)&weight, (void*)&bias, (void*)&out};
    hipLaunchCooperativeKernel((void*)pin_fused_kernel, grid, block, args, 0, stream);
}